// Round 8
// baseline (651.333 us; speedup 1.0000x reference)
//
#include <hip/hip_runtime.h>

#define GD 130              // grid extent per dim (G+2)
#define GD2 (GD*GD)
#define GRID_ELEMS (GD*GD*GD)
#define STATS_BYTES 1024
#define CHUNK 64            // consecutive rows per wave chunk
#define RB 4                // rows per probe batch (108 pairs -> 2 vector loads)
#define WPB 16              // waves per conv block (1024 threads)
#define CONV_BLOCKS 512     // 2 blocks/CU (cout-split halves), 32 waves/CU
#define MAX_NIN 100000
#define MAX_NOUT 1600000
#define WSTRIDE 5           // padded granule stride (conflict-free, R5-verified)

typedef _Float16 h2 __attribute__((ext_vector_type(2)));

__device__ _Float16 g_feat16[MAX_NIN * 32];            // 6.4 MB
__device__ _Float16 g_out16[(size_t)MAX_NOUT * 64];    // 204.8 MB intermediate

__device__ __forceinline__ float dot2(unsigned int f, unsigned int w, float acc) {
    union { unsigned int u; h2 h; } a, b;
    a.u = f; b.u = w;
    return __builtin_amdgcn_fdot2(a.h, b.h, acc, false);
}

__global__ __launch_bounds__(256) void scatter_grid_k(
    const int* __restrict__ pos, int* __restrict__ grid, int n_in)
{
    int i = blockIdx.x * blockDim.x + threadIdx.x;
    if (i < n_in) {
        int x = pos[3*i], y = pos[3*i+1], z = pos[3*i+2];
        grid[(x*GD + y)*GD + z] = i;
    }
}

__global__ __launch_bounds__(256) void feat_to_f16_k(
    const float* __restrict__ feat, int n32)
{
    int i = (blockIdx.x * blockDim.x + threadIdx.x) * 8;
    if (i < n32) {
        const float4 a = *reinterpret_cast<const float4*>(feat + i);
        const float4 b = *reinterpret_cast<const float4*>(feat + i + 4);
        union { _Float16 h[8]; uint4 u; } t;
        t.h[0] = (_Float16)a.x; t.h[1] = (_Float16)a.y;
        t.h[2] = (_Float16)a.z; t.h[3] = (_Float16)a.w;
        t.h[4] = (_Float16)b.x; t.h[5] = (_Float16)b.y;
        t.h[6] = (_Float16)b.z; t.h[7] = (_Float16)b.w;
        *reinterpret_cast<uint4*>(g_feat16 + i) = t.u;
    }
}

#define FLUSH(R, A0, A1) {                                                    \
    const float _a = (A0) + (A1);                                             \
    const float _p = __shfl_xor(_a, 32);                                      \
    if (lane < 32) {                                                          \
        const float _f = _a + _p;                                             \
        g_out16[(size_t)(R) * 64 + coutg] = (_Float16)_f;                     \
        ssum += _f; ssq = fmaf(_f, _f, ssq);                                  \
    } }

// Process one 64-bit occupancy mask: iterate set bits (occupied taps),
// rolling accumulator flushed on row change. All control flow wave-uniform.
// Each lane handles cout = oc (lane&31) for cin half (lane>>5).
#define PROCESS_MASK(MASK, VIDX, POFF)                                        \
    while (MASK) {                                                            \
        const int s = (int)__builtin_ctzll(MASK);                             \
        MASK &= MASK - 1;                                                     \
        const int p = s + (POFF);                                             \
        const int r = (p * 19) >> 9;          /* p/27 for p<108 */            \
        const int t = p - 27 * r;                                             \
        const int idx = __builtin_amdgcn_readlane(VIDX, s);                   \
        const int rowg = row0 + r;                                            \
        if (rowg != cur_r) {                                                  \
            if (cur_r >= 0) FLUSH(cur_r, a0, a1)                              \
            cur_r = rowg; a0 = 0.f; a1 = 0.f;                                 \
        }                                                                     \
        const uint4* fp = reinterpret_cast<const uint4*>(                     \
            g_feat16 + (size_t)idx * 32) + chg;                               \
        const uint4* wrow = wlds + (t * 32 + oc) * WSTRIDE + chg;             \
        const uint4 f0 = fp[0], f1 = fp[1];                                   \
        const uint4 w0 = wrow[0], w1 = wrow[1];                               \
        a0 = dot2(f0.x, w0.x, a0); a1 = dot2(f0.y, w0.y, a1);                 \
        a0 = dot2(f0.z, w0.z, a0); a1 = dot2(f0.w, w0.w, a1);                 \
        a0 = dot2(f1.x, w1.x, a0); a1 = dot2(f1.y, w1.y, a1);                 \
        a0 = dot2(f1.z, w1.z, a0); a1 = dot2(f1.w, w1.w, a1);                 \
    }

__global__ __launch_bounds__(1024, 8) void conv_stats_k(
    const float* __restrict__ W,
    const int* __restrict__ outpos, const int* __restrict__ grid,
    float* __restrict__ stats, int n_out)
{
    __shared__ uint4 wlds[27*32*WSTRIDE];   // 69,120 B -> 2 blocks/CU
    __shared__ float sstat[64];

    const int tid  = threadIdx.x;
    const int lane = tid & 63;
    const int wid  = tid >> 6;
    const int h    = blockIdx.x & 1;        // cout half
    const int oc   = lane & 31;             // cout offset within half
    const int chg  = (lane >> 5) * 2;       // cin-half granule offset
    const int coutg = h * 32 + oc;          // global cout (lanes<32 write)

    // stage W: global [k][cin][cout] f32 -> LDS [k][oc][granule] f16 (half couts)
    for (int g = tid; g < 27*32*4; g += 1024) {
        const int k   = g >> 7;
        const int rem = g & 127;
        const int o   = rem >> 2;           // oc
        const int q   = rem & 3;            // granule (8 cin)
        union { _Float16 hh[8]; uint4 u; } t;
        #pragma unroll
        for (int j = 0; j < 8; ++j)
            t.hh[j] = (_Float16)W[k*2048 + (q*8 + j)*64 + h*32 + o];
        wlds[(k*32 + o)*WSTRIDE + q] = t.u;
    }
    if (tid < 64) sstat[tid] = 0.f;
    __syncthreads();

    // per-lane (row,tap) pair decomposition for the two probe loads
    const int pA = lane;                      // pairs 0..63
    const int pB = lane + 64;                 // pairs 64..107 (lanes 0..43)
    const int rA = (pA * 19) >> 9;
    const int tA = pA - 27 * rA;
    const int rBv = (pB * 19) >> 9;
    const int tB = pB - 27 * rBv;
    const bool laneB = (lane < 44);

    // tap -> grid offset
    auto coff = [](int t) {
        const int dx  = (t * 114) >> 10;      // t/9
        const int rem = t - 9 * dx;
        const int dy  = (rem * 11) >> 5;      // rem/3
        const int dz  = rem - 3 * dy;
        return dx * GD2 + dy * GD + dz;
    };
    const int cA = coff(tA);
    const int cB = coff(tB);

    // probe a batch of RB rows starting at row0 -> per-lane tap indices
    auto probe = [&](int row0, int& iA, int& iB) {
        const int rowA = row0 + rA;
        const int rowB = row0 + rBv;
        const int raC = min(rowA, n_out - 1);
        const int rbC = min(rowB, n_out - 1);
        const int xA = outpos[3*raC], yA = outpos[3*raC+1], zA = outpos[3*raC+2];
        const int xB = outpos[3*rbC], yB = outpos[3*rbC+1], zB = outpos[3*rbC+2];
        int a = grid[(xA*GD + yA)*GD + zA + cA];
        int b = grid[(xB*GD + yB)*GD + zB + cB];
        if (rowA >= n_out) a = -1;
        if (!laneB || rowB >= n_out) b = -1;
        iA = a; iB = b;
    };

    const int gw = (blockIdx.x >> 1) * WPB + wid;
    const int nw = (gridDim.x >> 1) * WPB;
    const int nchunks = (n_out + CHUNK - 1) / CHUNK;
    const int NB = CHUNK / RB;

    float ssum = 0.f, ssq = 0.f;

    for (int ch = gw; ch < nchunks; ch += nw) {
        const int rbase = ch * CHUNK;
        int iA_c, iB_c;
        probe(rbase, iA_c, iB_c);             // prefetch batch 0

        for (int b = 0; b < NB; ++b) {
            const int row0 = rbase + b * RB;
            if (row0 >= n_out) break;

            unsigned long long m0 = __ballot(iA_c >= 0);
            unsigned long long m1 = __ballot(iB_c >= 0);

            // issue next batch's probe loads before processing (latency hiding)
            int iA_n = -1, iB_n = -1;
            const int row0n = row0 + RB;
            if (b + 1 < NB && row0n < n_out) probe(row0n, iA_n, iB_n);

            int cur_r = -1;
            float a0 = 0.f, a1 = 0.f;

            PROCESS_MASK(m0, iA_c, 0)
            PROCESS_MASK(m1, iB_c, 64)

            if (cur_r >= 0) FLUSH(cur_r, a0, a1)

            iA_c = iA_n; iB_c = iB_n;
        }
    }

    // block reduction via LDS atomics, then one global atomic per channel
    atomicAdd(&sstat[oc],      ssum);   // lanes>=32 add 0
    atomicAdd(&sstat[32 + oc], ssq);
    __syncthreads();
    if (tid < 32)       unsafeAtomicAdd(&stats[h*32 + tid], sstat[tid]);
    else if (tid < 64)  unsafeAtomicAdd(&stats[64 + h*32 + (tid-32)], sstat[tid]);
}

__global__ __launch_bounds__(256) void bn_relu_k(
    float* __restrict__ out, const float* __restrict__ stats,
    const float* __restrict__ gamma, const float* __restrict__ beta, int n_out)
{
    __shared__ float sc[64], sh[64];
    if (threadIdx.x < 64) {
        const int c = threadIdx.x;
        const double inv_n = 1.0 / (double)n_out;
        const double mean = (double)stats[c] * inv_n;
        const double var  = (double)stats[64 + c] * inv_n - mean * mean;
        const float scale = gamma[c] * rsqrtf((float)var + 1e-5f);
        sc[c] = scale;
        sh[c] = beta[c] - (float)mean * scale;
    }
    __syncthreads();

    const size_t total8 = (size_t)n_out * 8;    // 8 halves per thread-iter
    for (size_t t = (size_t)blockIdx.x * blockDim.x + threadIdx.x;
         t < total8; t += (size_t)gridDim.x * blockDim.x) {
        union { uint4 u; _Float16 h[8]; } v;
        v.u = *reinterpret_cast<const uint4*>(g_out16 + t * 8);
        const int c0 = ((int)(t & 7)) * 8;
        float4 r0, r1;
        r0.x = fmaxf(fmaf((float)v.h[0], sc[c0+0], sh[c0+0]), 0.f);
        r0.y = fmaxf(fmaf((float)v.h[1], sc[c0+1], sh[c0+1]), 0.f);
        r0.z = fmaxf(fmaf((float)v.h[2], sc[c0+2], sh[c0+2]), 0.f);
        r0.w = fmaxf(fmaf((float)v.h[3], sc[c0+3], sh[c0+3]), 0.f);
        r1.x = fmaxf(fmaf((float)v.h[4], sc[c0+4], sh[c0+4]), 0.f);
        r1.y = fmaxf(fmaf((float)v.h[5], sc[c0+5], sh[c0+5]), 0.f);
        r1.z = fmaxf(fmaf((float)v.h[6], sc[c0+6], sh[c0+6]), 0.f);
        r1.w = fmaxf(fmaf((float)v.h[7], sc[c0+7], sh[c0+7]), 0.f);
        float4* o4 = reinterpret_cast<float4*>(out + t * 8);
        o4[0] = r0;
        o4[1] = r1;
    }
}

extern "C" void kernel_launch(void* const* d_in, const int* in_sizes, int n_in_arrs,
                              void* d_out, int out_size, void* d_ws, size_t ws_size,
                              hipStream_t stream)
{
    const float* feat   = (const float*)d_in[0];
    const float* W      = (const float*)d_in[1];
    const float* gamma  = (const float*)d_in[2];
    const float* beta   = (const float*)d_in[3];
    const int*   pos    = (const int*)d_in[4];
    const int*   outpos = (const int*)d_in[5];

    const int n_in  = in_sizes[0] / 32;
    const int n_out = in_sizes[5] / 3;

    float* out   = (float*)d_out;
    float* stats = (float*)d_ws;
    int*   grid  = (int*)((char*)d_ws + STATS_BYTES);

    hipMemsetAsync(stats, 0, STATS_BYTES, stream);
    hipMemsetAsync(grid, 0xFF, (size_t)GRID_ELEMS * 4, stream);   // int -1

    scatter_grid_k<<<(n_in + 255) / 256, 256, 0, stream>>>(pos, grid, n_in);
    feat_to_f16_k<<<(n_in * 32 / 8 + 255) / 256, 256, 0, stream>>>(feat, n_in * 32);
    conv_stats_k<<<CONV_BLOCKS, 1024, 0, stream>>>(W, outpos, grid, stats, n_out);
    bn_relu_k<<<2048, 256, 0, stream>>>(out, stats, gamma, beta, n_out);
}

// Round 9
// 560.452 us; speedup vs baseline: 1.1622x; 1.1622x over previous
//
#include <hip/hip_runtime.h>

#define GD 130              // grid extent per dim (G+2)
#define GD2 (GD*GD)
#define GRID_ELEMS (GD*GD*GD)
#define STATS_BYTES 1024
#define CHUNK 64            // consecutive rows per wave chunk
#define RB 4                // rows per probe batch (108 pairs -> 2 masks)
#define WPB 16              // waves per conv block (1024 threads)
#define CONV_BLOCKS 256
#define MAX_NIN 100000
#define MAX_NOUT 1600000
#define WSTRIDE 5           // padded granule stride (conflict-free, R5-verified)

typedef _Float16 h2 __attribute__((ext_vector_type(2)));

__device__ _Float16 g_feat16[MAX_NIN * 32];            // 6.4 MB
__device__ _Float16 g_out16[(size_t)MAX_NOUT * 64];    // 204.8 MB intermediate

__device__ __forceinline__ float dot2(unsigned int f, unsigned int w, float acc) {
    union { unsigned int u; h2 h; } a, b;
    a.u = f; b.u = w;
    return __builtin_amdgcn_fdot2(a.h, b.h, acc, false);
}

__global__ __launch_bounds__(256) void scatter_grid_k(
    const int* __restrict__ pos, int* __restrict__ grid, int n_in)
{
    int i = blockIdx.x * blockDim.x + threadIdx.x;
    if (i < n_in) {
        int x = pos[3*i], y = pos[3*i+1], z = pos[3*i+2];
        grid[(x*GD + y)*GD + z] = i;
    }
}

__global__ __launch_bounds__(256) void feat_to_f16_k(
    const float* __restrict__ feat, int n32)
{
    int i = (blockIdx.x * blockDim.x + threadIdx.x) * 8;
    if (i < n32) {
        const float4 a = *reinterpret_cast<const float4*>(feat + i);
        const float4 b = *reinterpret_cast<const float4*>(feat + i + 4);
        union { _Float16 h[8]; uint4 u; } t;
        t.h[0] = (_Float16)a.x; t.h[1] = (_Float16)a.y;
        t.h[2] = (_Float16)a.z; t.h[3] = (_Float16)a.w;
        t.h[4] = (_Float16)b.x; t.h[5] = (_Float16)b.y;
        t.h[6] = (_Float16)b.z; t.h[7] = (_Float16)b.w;
        *reinterpret_cast<uint4*>(g_feat16 + i) = t.u;
    }
}

#define FLUSH(R, A0, A1) {                                                    \
    const float _a = (A0) + (A1);                                             \
    g_out16[(size_t)(R) * 64 + lane] = (_Float16)_a;                          \
    ssum += _a; ssq = fmaf(_a, _a, ssq); }

// Probe batch of RB rows at ROW0: per-lane (row,tap) occupancy indices AND
// per-lane gather of that pair's 32-cin feat row into registers (4 uint4).
#define PROBE(ROW0, IA, IB, FA0,FA1,FA2,FA3, FB0,FB1,FB2,FB3) {               \
    const int rowA = (ROW0) + rA;                                             \
    const int rowB = (ROW0) + rBv;                                            \
    const int raC = min(rowA, n_out - 1);                                     \
    const int rbC = min(rowB, n_out - 1);                                     \
    const int xA = outpos[3*raC], yA = outpos[3*raC+1], zA = outpos[3*raC+2]; \
    const int xB = outpos[3*rbC], yB = outpos[3*rbC+1], zB = outpos[3*rbC+2]; \
    int _a = grid[(xA*GD + yA)*GD + zA + cA];                                 \
    int _b = grid[(xB*GD + yB)*GD + zB + cB];                                 \
    if (rowA >= n_out) _a = -1;                                               \
    if (!laneB || rowB >= n_out) _b = -1;                                     \
    IA = _a; IB = _b;                                                         \
    if (_a >= 0) {                                                            \
        const uint4* _fp = reinterpret_cast<const uint4*>(                    \
            g_feat16 + (size_t)_a * 32);                                      \
        FA0 = _fp[0]; FA1 = _fp[1]; FA2 = _fp[2]; FA3 = _fp[3];               \
    }                                                                         \
    if (_b >= 0) {                                                            \
        const uint4* _fp = reinterpret_cast<const uint4*>(                    \
            g_feat16 + (size_t)_b * 32);                                      \
        FB0 = _fp[0]; FB1 = _fp[1]; FB2 = _fp[2]; FB3 = _fp[3];               \
    } }

// Iterate set bits: feat via readlane (register broadcast, no memory),
// weights via LDS. Rolling accumulator flushed on row change.
#define PROCESS(MASK, F0, F1, F2, F3, POFF)                                   \
    while (MASK) {                                                            \
        const int s = (int)__builtin_ctzll(MASK);                             \
        MASK &= MASK - 1;                                                     \
        const int p = s + (POFF);                                             \
        const int r = (p * 19) >> 9;          /* p/27 for p<108 */            \
        const int t = p - 27 * r;                                             \
        const int rowg = row0 + r;                                            \
        if (rowg != cur_r) {                                                  \
            if (cur_r >= 0) FLUSH(cur_r, a0, a1)                              \
            cur_r = rowg; a0 = 0.f; a1 = 0.f;                                 \
        }                                                                     \
        const uint4* wrow = wlds + (t * 64 + lane) * WSTRIDE;                 \
        const uint4 w0 = wrow[0], w1 = wrow[1];                               \
        const uint4 w2 = wrow[2], w3 = wrow[3];                               \
        const unsigned g0 = __builtin_amdgcn_readlane(F0.x, s);               \
        const unsigned g1 = __builtin_amdgcn_readlane(F0.y, s);               \
        const unsigned g2 = __builtin_amdgcn_readlane(F0.z, s);               \
        const unsigned g3 = __builtin_amdgcn_readlane(F0.w, s);               \
        const unsigned g4 = __builtin_amdgcn_readlane(F1.x, s);               \
        const unsigned g5 = __builtin_amdgcn_readlane(F1.y, s);               \
        const unsigned g6 = __builtin_amdgcn_readlane(F1.z, s);               \
        const unsigned g7 = __builtin_amdgcn_readlane(F1.w, s);               \
        const unsigned g8 = __builtin_amdgcn_readlane(F2.x, s);               \
        const unsigned g9 = __builtin_amdgcn_readlane(F2.y, s);               \
        const unsigned gA = __builtin_amdgcn_readlane(F2.z, s);               \
        const unsigned gB = __builtin_amdgcn_readlane(F2.w, s);               \
        const unsigned gC = __builtin_amdgcn_readlane(F3.x, s);               \
        const unsigned gD = __builtin_amdgcn_readlane(F3.y, s);               \
        const unsigned gE = __builtin_amdgcn_readlane(F3.z, s);               \
        const unsigned gF = __builtin_amdgcn_readlane(F3.w, s);               \
        a0 = dot2(g0, w0.x, a0); a1 = dot2(g1, w0.y, a1);                     \
        a0 = dot2(g2, w0.z, a0); a1 = dot2(g3, w0.w, a1);                     \
        a0 = dot2(g4, w1.x, a0); a1 = dot2(g5, w1.y, a1);                     \
        a0 = dot2(g6, w1.z, a0); a1 = dot2(g7, w1.w, a1);                     \
        a0 = dot2(g8, w2.x, a0); a1 = dot2(g9, w2.y, a1);                     \
        a0 = dot2(gA, w2.z, a0); a1 = dot2(gB, w2.w, a1);                     \
        a0 = dot2(gC, w3.x, a0); a1 = dot2(gD, w3.y, a1);                     \
        a0 = dot2(gE, w3.z, a0); a1 = dot2(gF, w3.w, a1);                     \
    }

#define PROCESS_BATCH(ROW0, IA, IB, FA0,FA1,FA2,FA3, FB0,FB1,FB2,FB3) {       \
    const int row0 = (ROW0);                                                  \
    unsigned long long mA = __ballot(IA >= 0);                                \
    unsigned long long mB = __ballot(IB >= 0);                                \
    int cur_r = -1;                                                           \
    float a0 = 0.f, a1 = 0.f;                                                 \
    PROCESS(mA, FA0, FA1, FA2, FA3, 0)                                        \
    PROCESS(mB, FB0, FB1, FB2, FB3, 64)                                       \
    if (cur_r >= 0) FLUSH(cur_r, a0, a1) }

__global__ __launch_bounds__(1024, 4) void conv_stats_k(
    const float* __restrict__ W,
    const int* __restrict__ outpos, const int* __restrict__ grid,
    float* __restrict__ stats, int n_out)
{
    __shared__ uint4 wlds[27*64*WSTRIDE];   // 138,240 B
    __shared__ float sstat[128];

    const int tid  = threadIdx.x;
    const int lane = tid & 63;
    const int wid  = tid >> 6;

    // stage W: global [k][cin][cout] f32 -> LDS [k][cout][granule] f16
    for (int g = tid; g < 27*64*4; g += 1024) {
        const int k   = g >> 8;
        const int rem = g & 255;
        const int o   = rem >> 2;
        const int q   = rem & 3;
        union { _Float16 h[8]; uint4 u; } t;
        #pragma unroll
        for (int j = 0; j < 8; ++j)
            t.h[j] = (_Float16)W[k*2048 + (q*8 + j)*64 + o];
        wlds[(k*64 + o)*WSTRIDE + q] = t.u;
    }
    if (tid < 128) sstat[tid] = 0.f;
    __syncthreads();

    // per-lane (row,tap) pair decomposition
    const int pA = lane;                      // pairs 0..63
    const int pB = lane + 64;                 // pairs 64..107 (lanes 0..43)
    const int rA = (pA * 19) >> 9;
    const int tA = pA - 27 * rA;
    const int rBv = (pB * 19) >> 9;
    const int tB = pB - 27 * rBv;
    const bool laneB = (lane < 44);

    auto coff = [](int t) {
        const int dx  = (t * 114) >> 10;
        const int rem = t - 9 * dx;
        const int dy  = (rem * 11) >> 5;
        const int dz  = rem - 3 * dy;
        return dx * GD2 + dy * GD + dz;
    };
    const int cA = coff(tA);
    const int cB = coff(tB);

    const int gw = blockIdx.x * WPB + wid;
    const int nw = gridDim.x * WPB;
    const int nchunks = (n_out + CHUNK - 1) / CHUNK;
    const int NB = CHUNK / RB;                // 16 (even)

    float ssum = 0.f, ssq = 0.f;

    int iA0, iB0, iA1, iB1;
    uint4 fA00, fA01, fA02, fA03, fB00, fB01, fB02, fB03;
    uint4 fA10, fA11, fA12, fA13, fB10, fB11, fB12, fB13;

    for (int ch = gw; ch < nchunks; ch += nw) {
        const int rbase = ch * CHUNK;
        PROBE(rbase, iA0, iB0, fA00,fA01,fA02,fA03, fB00,fB01,fB02,fB03)

        #pragma unroll 1
        for (int b = 0; b < NB; b += 2) {
            const int r0 = rbase + b * RB;
            // prefetch batch b+1 into set1 while processing set0
            PROBE(r0 + RB, iA1, iB1, fA10,fA11,fA12,fA13, fB10,fB11,fB12,fB13)
            PROCESS_BATCH(r0, iA0, iB0, fA00,fA01,fA02,fA03, fB00,fB01,fB02,fB03)
            // prefetch batch b+2 into set0 (skip at chunk end)
            if (b + 2 < NB) {
                PROBE(r0 + 2*RB, iA0, iB0, fA00,fA01,fA02,fA03, fB00,fB01,fB02,fB03)
            }
            PROCESS_BATCH(r0 + RB, iA1, iB1, fA10,fA11,fA12,fA13, fB10,fB11,fB12,fB13)
        }
    }

    atomicAdd(&sstat[lane],      ssum);
    atomicAdd(&sstat[64 + lane], ssq);
    __syncthreads();
    if (tid < 128) unsafeAtomicAdd(&stats[tid], sstat[tid]);
}

__global__ __launch_bounds__(256) void bn_relu_k(
    float* __restrict__ out, const float* __restrict__ stats,
    const float* __restrict__ gamma, const float* __restrict__ beta, int n_out)
{
    __shared__ float sc[64], sh[64];
    if (threadIdx.x < 64) {
        const int c = threadIdx.x;
        const double inv_n = 1.0 / (double)n_out;
        const double mean = (double)stats[c] * inv_n;
        const double var  = (double)stats[64 + c] * inv_n - mean * mean;
        const float scale = gamma[c] * rsqrtf((float)var + 1e-5f);
        sc[c] = scale;
        sh[c] = beta[c] - (float)mean * scale;
    }
    __syncthreads();

    const size_t total8 = (size_t)n_out * 8;
    for (size_t t = (size_t)blockIdx.x * blockDim.x + threadIdx.x;
         t < total8; t += (size_t)gridDim.x * blockDim.x) {
        union { uint4 u; _Float16 h[8]; } v;
        v.u = *reinterpret_cast<const uint4*>(g_out16 + t * 8);
        const int c0 = ((int)(t & 7)) * 8;
        float4 r0, r1;
        r0.x = fmaxf(fmaf((float)v.h[0], sc[c0+0], sh[c0+0]), 0.f);
        r0.y = fmaxf(fmaf((float)v.h[1], sc[c0+1], sh[c0+1]), 0.f);
        r0.z = fmaxf(fmaf((float)v.h[2], sc[c0+2], sh[c0+2]), 0.f);
        r0.w = fmaxf(fmaf((float)v.h[3], sc[c0+3], sh[c0+3]), 0.f);
        r1.x = fmaxf(fmaf((float)v.h[4], sc[c0+4], sh[c0+4]), 0.f);
        r1.y = fmaxf(fmaf((float)v.h[5], sc[c0+5], sh[c0+5]), 0.f);
        r1.z = fmaxf(fmaf((float)v.h[6], sc[c0+6], sh[c0+6]), 0.f);
        r1.w = fmaxf(fmaf((float)v.h[7], sc[c0+7], sh[c0+7]), 0.f);
        float4* o4 = reinterpret_cast<float4*>(out + t * 8);
        o4[0] = r0;
        o4[1] = r1;
    }
}

extern "C" void kernel_launch(void* const* d_in, const int* in_sizes, int n_in_arrs,
                              void* d_out, int out_size, void* d_ws, size_t ws_size,
                              hipStream_t stream)
{
    const float* feat   = (const float*)d_in[0];
    const float* W      = (const float*)d_in[1];
    const float* gamma  = (const float*)d_in[2];
    const float* beta   = (const float*)d_in[3];
    const int*   pos    = (const int*)d_in[4];
    const int*   outpos = (const int*)d_in[5];

    const int n_in  = in_sizes[0] / 32;
    const int n_out = in_sizes[5] / 3;

    float* out   = (float*)d_out;
    float* stats = (float*)d_ws;
    int*   grid  = (int*)((char*)d_ws + STATS_BYTES);

    hipMemsetAsync(stats, 0, STATS_BYTES, stream);
    hipMemsetAsync(grid, 0xFF, (size_t)GRID_ELEMS * 4, stream);   // int -1

    scatter_grid_k<<<(n_in + 255) / 256, 256, 0, stream>>>(pos, grid, n_in);
    feat_to_f16_k<<<(n_in * 32 / 8 + 255) / 256, 256, 0, stream>>>(feat, n_in * 32);
    conv_stats_k<<<CONV_BLOCKS, 1024, 0, stream>>>(W, outpos, grid, stats, n_out);
    bn_relu_k<<<2048, 256, 0, stream>>>(out, stats, gamma, beta, n_out);
}